// Round 1
// baseline (1493.466 us; speedup 1.0000x reference)
//
#include <hip/hip_runtime.h>
#include <math.h>

#define B 8
#define C 512
#define L 2048
#define CQ 128
#define O_TOT 768  // CQ (q) + CQ (k) + C (v)

// ---------------------------------------------------------------------------
// K1: fused QKV projection.  y[b,o,l] = sum_c W[o,c] * x[b,c,l] + bias[o]
//     o in [0,128) -> q_w ; [128,256) -> k_w ; [256,768) -> v_w
//     64x64 tile, K-chunk 16, 4x4 microtile per thread (256 threads).
// ---------------------------------------------------------------------------
__global__ __launch_bounds__(256) void proj_kernel(
    const float* __restrict__ x,
    const float* __restrict__ qw, const float* __restrict__ qb,
    const float* __restrict__ kw, const float* __restrict__ kb,
    const float* __restrict__ vw, const float* __restrict__ vb,
    float* __restrict__ y)
{
    const int b  = blockIdx.z;
    const int o0 = blockIdx.y * 64;
    const int l0 = blockIdx.x * 64;
    const int tid = threadIdx.x;
    const int tx = tid & 15;   // n (l) group: 16 x 4 = 64
    const int ty = tid >> 4;   // m (o) group: 16 x 4 = 64

    __shared__ float As[16][64];   // [c][o]
    __shared__ float Bs[16][64];   // [c][l]

    float acc[4][4] = {};
    const float* xb = x + (size_t)b * C * L;

    for (int c0 = 0; c0 < C; c0 += 16) {
        // A tile (W): stride-1 LDS writes; o-range is block-uniform (o0 % 64 == 0,
        // range boundaries 128/256 are multiples of 64 -> uniform branch).
        #pragma unroll
        for (int r = 0; r < 4; ++r) {
            int idx = tid + r * 256;
            int oo = idx & 63;
            int cc = idx >> 6;
            int o = o0 + oo;
            int c = c0 + cc;
            float w;
            if (o0 < CQ)           w = qw[o * C + c];
            else if (o0 < 2 * CQ)  w = kw[(o - CQ) * C + c];
            else                   w = vw[(o - 2 * CQ) * C + c];
            As[cc][oo] = w;
        }
        // B tile (x): coalesced along l.
        #pragma unroll
        for (int r = 0; r < 4; ++r) {
            int idx = tid + r * 256;
            int ll = idx & 63;
            int cc = idx >> 6;
            Bs[cc][ll] = xb[(size_t)(c0 + cc) * L + l0 + ll];
        }
        __syncthreads();
        #pragma unroll
        for (int kk = 0; kk < 16; ++kk) {
            float4 a4 = *(const float4*)(&As[kk][ty * 4]);
            float4 b4 = *(const float4*)(&Bs[kk][tx * 4]);
            float av[4] = {a4.x, a4.y, a4.z, a4.w};
            float bv[4] = {b4.x, b4.y, b4.z, b4.w};
            #pragma unroll
            for (int i = 0; i < 4; ++i)
                #pragma unroll
                for (int j = 0; j < 4; ++j)
                    acc[i][j] = fmaf(av[i], bv[j], acc[i][j]);
        }
        __syncthreads();
    }

    #pragma unroll
    for (int i = 0; i < 4; ++i) {
        int o = o0 + ty * 4 + i;
        float bias;
        if (o0 < CQ)           bias = qb[o];
        else if (o0 < 2 * CQ)  bias = kb[o - CQ];
        else                   bias = vb[o - 2 * CQ];
        size_t off = ((size_t)b * O_TOT + o) * L + l0 + tx * 4;
        float4 r;
        r.x = acc[i][0] + bias;
        r.y = acc[i][1] + bias;
        r.z = acc[i][2] + bias;
        r.w = acc[i][3] + bias;
        *(float4*)(y + off) = r;
    }
}

// ---------------------------------------------------------------------------
// K2: energy[b,i,j] = sum_d q[b,d,i] * k[b,d,j]   (K = 128)
//     q = y[b, 0:128, :], k = y[b, 128:256, :]  (d-major, i/j contiguous)
// ---------------------------------------------------------------------------
__global__ __launch_bounds__(256) void energy_kernel(
    const float* __restrict__ y, float* __restrict__ attn)
{
    const int b  = blockIdx.z;
    const int i0 = blockIdx.y * 64;
    const int j0 = blockIdx.x * 64;
    const int tid = threadIdx.x;
    const int tx = tid & 15;   // j group
    const int ty = tid >> 4;   // i group

    const float* q = y + ((size_t)b * O_TOT + 0)  * L;
    const float* k = y + ((size_t)b * O_TOT + CQ) * L;

    __shared__ float Qs[16][64];   // [d][i]
    __shared__ float Ks[16][64];   // [d][j]

    float acc[4][4] = {};

    for (int d0 = 0; d0 < CQ; d0 += 16) {
        #pragma unroll
        for (int r = 0; r < 4; ++r) {
            int idx = tid + r * 256;
            int ii = idx & 63;
            int dd = idx >> 6;
            Qs[dd][ii] = q[(size_t)(d0 + dd) * L + i0 + ii];
        }
        #pragma unroll
        for (int r = 0; r < 4; ++r) {
            int idx = tid + r * 256;
            int jj = idx & 63;
            int dd = idx >> 6;
            Ks[dd][jj] = k[(size_t)(d0 + dd) * L + j0 + jj];
        }
        __syncthreads();
        #pragma unroll
        for (int kk = 0; kk < 16; ++kk) {
            float4 a4 = *(const float4*)(&Qs[kk][ty * 4]);
            float4 b4 = *(const float4*)(&Ks[kk][tx * 4]);
            float av[4] = {a4.x, a4.y, a4.z, a4.w};
            float bv[4] = {b4.x, b4.y, b4.z, b4.w};
            #pragma unroll
            for (int i = 0; i < 4; ++i)
                #pragma unroll
                for (int j = 0; j < 4; ++j)
                    acc[i][j] = fmaf(av[i], bv[j], acc[i][j]);
        }
        __syncthreads();
    }

    #pragma unroll
    for (int i = 0; i < 4; ++i) {
        int ii = i0 + ty * 4 + i;
        size_t off = ((size_t)b * L + ii) * L + j0 + tx * 4;
        float4 r;
        r.x = acc[i][0]; r.y = acc[i][1]; r.z = acc[i][2]; r.w = acc[i][3];
        *(float4*)(attn + off) = r;
    }
}

// ---------------------------------------------------------------------------
// K3: in-place row softmax over attn rows of length L (one block per row)
// ---------------------------------------------------------------------------
__global__ __launch_bounds__(256) void softmax_kernel(float* __restrict__ attn)
{
    const size_t row = blockIdx.x;   // b*L + i
    float* p = attn + row * (size_t)L;
    const int tid = threadIdx.x;
    const int wave = tid >> 6, lane = tid & 63;

    float v[8];
    #pragma unroll
    for (int kk = 0; kk < 8; ++kk) v[kk] = p[tid + kk * 256];

    float m = v[0];
    #pragma unroll
    for (int kk = 1; kk < 8; ++kk) m = fmaxf(m, v[kk]);
    #pragma unroll
    for (int off = 32; off >= 1; off >>= 1) m = fmaxf(m, __shfl_xor(m, off));

    __shared__ float red[4];
    if (lane == 0) red[wave] = m;
    __syncthreads();
    m = fmaxf(fmaxf(red[0], red[1]), fmaxf(red[2], red[3]));
    __syncthreads();

    float s = 0.f;
    #pragma unroll
    for (int kk = 0; kk < 8; ++kk) { v[kk] = __expf(v[kk] - m); s += v[kk]; }
    #pragma unroll
    for (int off = 32; off >= 1; off >>= 1) s += __shfl_xor(s, off);
    if (lane == 0) red[wave] = s;
    __syncthreads();
    s = (red[0] + red[1]) + (red[2] + red[3]);

    const float inv = 1.0f / s;
    #pragma unroll
    for (int kk = 0; kk < 8; ++kk) p[tid + kk * 256] = v[kk] * inv;
}

// ---------------------------------------------------------------------------
// K4: out[b,c,i] = gamma * sum_j v[b,c,j] * attn[b,i,j] + x[b,c,i]
//     A = v (row-major along j), B = attn (row-major along j) -> C = A*B^T
// ---------------------------------------------------------------------------
__global__ __launch_bounds__(256) void out_kernel(
    const float* __restrict__ y, const float* __restrict__ attn,
    const float* __restrict__ x, const float* __restrict__ gamma,
    float* __restrict__ out)
{
    const int b  = blockIdx.z;
    const int c0 = blockIdx.y * 64;
    const int i0 = blockIdx.x * 64;
    const int tid = threadIdx.x;
    const int tx = tid & 15;   // i group
    const int ty = tid >> 4;   // c group

    const float* v  = y + ((size_t)b * O_TOT + 2 * CQ) * L;  // (C, L)
    const float* at = attn + (size_t)b * L * L;              // (L, L)

    __shared__ float Vs[16][64];   // [j][c]
    __shared__ float Ps[16][64];   // [j][i]

    float acc[4][4] = {};

    for (int j0 = 0; j0 < L; j0 += 16) {
        #pragma unroll
        for (int r = 0; r < 4; ++r) {
            int idx = tid + r * 256;
            int cc = idx & 63;
            int jj = idx >> 6;
            Vs[jj][cc] = v[(size_t)(c0 + cc) * L + j0 + jj];
        }
        #pragma unroll
        for (int r = 0; r < 4; ++r) {
            int idx = tid + r * 256;
            int ii = idx & 63;
            int jj = idx >> 6;
            Ps[jj][ii] = at[(size_t)(i0 + ii) * L + j0 + jj];
        }
        __syncthreads();
        #pragma unroll
        for (int kk = 0; kk < 16; ++kk) {
            float4 a4 = *(const float4*)(&Vs[kk][ty * 4]);
            float4 b4 = *(const float4*)(&Ps[kk][tx * 4]);
            float av[4] = {a4.x, a4.y, a4.z, a4.w};
            float bv[4] = {b4.x, b4.y, b4.z, b4.w};
            #pragma unroll
            for (int i = 0; i < 4; ++i)
                #pragma unroll
                for (int j = 0; j < 4; ++j)
                    acc[i][j] = fmaf(av[i], bv[j], acc[i][j]);
        }
        __syncthreads();
    }

    const float g = gamma[0];
    #pragma unroll
    for (int i = 0; i < 4; ++i) {
        int c = c0 + ty * 4 + i;
        size_t off = ((size_t)b * C + c) * L + i0 + tx * 4;
        float4 xv = *(const float4*)(x + off);
        float4 r;
        r.x = fmaf(g, acc[i][0], xv.x);
        r.y = fmaf(g, acc[i][1], xv.y);
        r.z = fmaf(g, acc[i][2], xv.z);
        r.w = fmaf(g, acc[i][3], xv.w);
        *(float4*)(out + off) = r;
    }
}

// ---------------------------------------------------------------------------
extern "C" void kernel_launch(void* const* d_in, const int* in_sizes, int n_in,
                              void* d_out, int out_size, void* d_ws, size_t ws_size,
                              hipStream_t stream)
{
    const float* x     = (const float*)d_in[0];
    const float* qw    = (const float*)d_in[1];
    const float* qb    = (const float*)d_in[2];
    const float* kw    = (const float*)d_in[3];
    const float* kb    = (const float*)d_in[4];
    const float* vw    = (const float*)d_in[5];
    const float* vb    = (const float*)d_in[6];
    const float* gamma = (const float*)d_in[7];

    float* out  = (float*)d_out;                       // (B, C, L)
    float* attn = (float*)d_out + (size_t)B * C * L;   // (B, L, L)
    float* y    = (float*)d_ws;                        // (B, 768, L): q|k|v

    proj_kernel<<<dim3(L / 64, O_TOT / 64, B), 256, 0, stream>>>(
        x, qw, qb, kw, kb, vw, vb, y);
    energy_kernel<<<dim3(L / 64, L / 64, B), 256, 0, stream>>>(y, attn);
    softmax_kernel<<<B * L, 256, 0, stream>>>(attn);
    out_kernel<<<dim3(L / 64, C / 64, B), 256, 0, stream>>>(
        y, attn, x, gamma, out);
}

// Round 2
// 628.932 us; speedup vs baseline: 2.3746x; 2.3746x over previous
//
#include <hip/hip_runtime.h>
#include <math.h>

#define B 8
#define C 512
#define L 2048
#define CQ 128

// MFMA fragment types (gfx950 mfma_f32_16x16x32_bf16: 8 bf16 in / 4 f32 acc)
using frag_ab = __attribute__((ext_vector_type(8))) short;
using f32x4   = __attribute__((ext_vector_type(4))) float;

__device__ __forceinline__ unsigned short f2bf(float f) {
    union { float f; unsigned int u; } v; v.f = f;
    unsigned int u = v.u + 0x7FFFu + ((v.u >> 16) & 1u);  // RNE
    return (unsigned short)(u >> 16);
}

__device__ __forceinline__ void gload_lds16(const void* g, void* l) {
    __builtin_amdgcn_global_load_lds(
        (__attribute__((address_space(1))) void*)g,
        (__attribute__((address_space(3))) void*)l, 16, 0, 0);
}

// ---------------------------------------------------------------------------
// K1: fused QKV projection. q,k -> fp32 y (B, 256, L); v -> bf16 vbf (B, C, L)
// ---------------------------------------------------------------------------
__global__ __launch_bounds__(256) void proj_kernel(
    const float* __restrict__ x,
    const float* __restrict__ qw, const float* __restrict__ qb,
    const float* __restrict__ kw, const float* __restrict__ kb,
    const float* __restrict__ vw, const float* __restrict__ vb,
    float* __restrict__ y, unsigned short* __restrict__ vbf)
{
    const int b  = blockIdx.z;
    const int o0 = blockIdx.y * 64;   // 0..767 over q|k|v
    const int l0 = blockIdx.x * 64;
    const int tid = threadIdx.x;
    const int tx = tid & 15;
    const int ty = tid >> 4;

    __shared__ float As[16][64];   // [c][o]
    __shared__ float Bs[16][64];   // [c][l]

    float acc[4][4] = {};
    const float* xb = x + (size_t)b * C * L;

    for (int c0 = 0; c0 < C; c0 += 16) {
        #pragma unroll
        for (int r = 0; r < 4; ++r) {
            int idx = tid + r * 256;
            int oo = idx & 63;
            int cc = idx >> 6;
            int o = o0 + oo;
            int c = c0 + cc;
            float w;
            if (o0 < CQ)           w = qw[o * C + c];
            else if (o0 < 2 * CQ)  w = kw[(o - CQ) * C + c];
            else                   w = vw[(o - 2 * CQ) * C + c];
            As[cc][oo] = w;
        }
        #pragma unroll
        for (int r = 0; r < 4; ++r) {
            int idx = tid + r * 256;
            int ll = idx & 63;
            int cc = idx >> 6;
            Bs[cc][ll] = xb[(size_t)(c0 + cc) * L + l0 + ll];
        }
        __syncthreads();
        #pragma unroll
        for (int kk = 0; kk < 16; ++kk) {
            float4 a4 = *(const float4*)(&As[kk][ty * 4]);
            float4 b4 = *(const float4*)(&Bs[kk][tx * 4]);
            float av[4] = {a4.x, a4.y, a4.z, a4.w};
            float bv[4] = {b4.x, b4.y, b4.z, b4.w};
            #pragma unroll
            for (int i = 0; i < 4; ++i)
                #pragma unroll
                for (int j = 0; j < 4; ++j)
                    acc[i][j] = fmaf(av[i], bv[j], acc[i][j]);
        }
        __syncthreads();
    }

    if (o0 < 2 * CQ) {
        // q|k -> fp32 into y (B, 256, L)
        #pragma unroll
        for (int i = 0; i < 4; ++i) {
            int o = o0 + ty * 4 + i;
            float bias = (o0 < CQ) ? qb[o] : kb[o - CQ];
            size_t off = ((size_t)b * 2 * CQ + o) * L + l0 + tx * 4;
            float4 r;
            r.x = acc[i][0] + bias;
            r.y = acc[i][1] + bias;
            r.z = acc[i][2] + bias;
            r.w = acc[i][3] + bias;
            *(float4*)(y + off) = r;
        }
    } else {
        // v -> bf16 into vbf (B, C, L)
        #pragma unroll
        for (int i = 0; i < 4; ++i) {
            int vo = o0 - 2 * CQ + ty * 4 + i;
            float bias = vb[vo];
            size_t off = ((size_t)b * C + vo) * L + l0 + tx * 4;
            ushort4 s;
            s.x = f2bf(acc[i][0] + bias);
            s.y = f2bf(acc[i][1] + bias);
            s.z = f2bf(acc[i][2] + bias);
            s.w = f2bf(acc[i][3] + bias);
            *(ushort4*)(vbf + off) = s;
        }
    }
}

// ---------------------------------------------------------------------------
// K2: energy[b,i,j] = sum_d q[b,d,i] * k[b,d,j]  (fp32 VALU, K = 128)
// ---------------------------------------------------------------------------
__global__ __launch_bounds__(256) void energy_kernel(
    const float* __restrict__ y, float* __restrict__ attn)
{
    const int b  = blockIdx.z;
    const int i0 = blockIdx.y * 64;
    const int j0 = blockIdx.x * 64;
    const int tid = threadIdx.x;
    const int tx = tid & 15;
    const int ty = tid >> 4;

    const float* q = y + (size_t)b * 2 * CQ * L;
    const float* k = q + (size_t)CQ * L;

    __shared__ float Qs[16][64];
    __shared__ float Ks[16][64];

    float acc[4][4] = {};

    for (int d0 = 0; d0 < CQ; d0 += 16) {
        #pragma unroll
        for (int r = 0; r < 4; ++r) {
            int idx = tid + r * 256;
            int ii = idx & 63;
            int dd = idx >> 6;
            Qs[dd][ii] = q[(size_t)(d0 + dd) * L + i0 + ii];
        }
        #pragma unroll
        for (int r = 0; r < 4; ++r) {
            int idx = tid + r * 256;
            int jj = idx & 63;
            int dd = idx >> 6;
            Ks[dd][jj] = k[(size_t)(d0 + dd) * L + j0 + jj];
        }
        __syncthreads();
        #pragma unroll
        for (int kk = 0; kk < 16; ++kk) {
            float4 a4 = *(const float4*)(&Qs[kk][ty * 4]);
            float4 b4 = *(const float4*)(&Ks[kk][tx * 4]);
            float av[4] = {a4.x, a4.y, a4.z, a4.w};
            float bv[4] = {b4.x, b4.y, b4.z, b4.w};
            #pragma unroll
            for (int i = 0; i < 4; ++i)
                #pragma unroll
                for (int j = 0; j < 4; ++j)
                    acc[i][j] = fmaf(av[i], bv[j], acc[i][j]);
        }
        __syncthreads();
    }

    #pragma unroll
    for (int i = 0; i < 4; ++i) {
        int ii = i0 + ty * 4 + i;
        size_t off = ((size_t)b * L + ii) * L + j0 + tx * 4;
        float4 r;
        r.x = acc[i][0]; r.y = acc[i][1]; r.z = acc[i][2]; r.w = acc[i][3];
        *(float4*)(attn + off) = r;
    }
}

// ---------------------------------------------------------------------------
// K3: row softmax; writes fp32 to attn (d_out) and bf16 copy to attnbf (ws)
// ---------------------------------------------------------------------------
__global__ __launch_bounds__(256) void softmax_kernel(
    float* __restrict__ attn, unsigned short* __restrict__ attnbf)
{
    const size_t row = blockIdx.x;   // b*L + i
    float* p = attn + row * (size_t)L;
    unsigned short* pb = attnbf + row * (size_t)L;
    const int tid = threadIdx.x;
    const int wave = tid >> 6, lane = tid & 63;

    float v[8];
    #pragma unroll
    for (int kk = 0; kk < 8; ++kk) v[kk] = p[tid + kk * 256];

    float m = v[0];
    #pragma unroll
    for (int kk = 1; kk < 8; ++kk) m = fmaxf(m, v[kk]);
    #pragma unroll
    for (int off = 32; off >= 1; off >>= 1) m = fmaxf(m, __shfl_xor(m, off));

    __shared__ float red[4];
    if (lane == 0) red[wave] = m;
    __syncthreads();
    m = fmaxf(fmaxf(red[0], red[1]), fmaxf(red[2], red[3]));
    __syncthreads();

    float s = 0.f;
    #pragma unroll
    for (int kk = 0; kk < 8; ++kk) { v[kk] = __expf(v[kk] - m); s += v[kk]; }
    #pragma unroll
    for (int off = 32; off >= 1; off >>= 1) s += __shfl_xor(s, off);
    if (lane == 0) red[wave] = s;
    __syncthreads();
    s = (red[0] + red[1]) + (red[2] + red[3]);

    const float inv = 1.0f / s;
    #pragma unroll
    for (int kk = 0; kk < 8; ++kk) {
        float r = v[kk] * inv;
        p[tid + kk * 256] = r;
        pb[tid + kk * 256] = f2bf(r);
    }
}

// ---------------------------------------------------------------------------
// K4: out[b,c,i] = gamma * sum_j v[c,j]*attn[i,j] + x[c,i]   (bf16 MFMA)
//     128x128 tile, BK=32, 4 waves each 64x64 via 4x4 of 16x16x32 MFMAs.
//     A = vbf rows (c, contig j); B = attnbf rows (i, contig j)  [C = A*B^T]
// ---------------------------------------------------------------------------
__global__ __launch_bounds__(256) void out_mfma_kernel(
    const unsigned short* __restrict__ vbf,
    const unsigned short* __restrict__ attnbf,
    const float* __restrict__ x, const float* __restrict__ gamma,
    float* __restrict__ out)
{
    const int b  = blockIdx.z;
    const int c0 = blockIdx.y * 128;
    const int i0 = blockIdx.x * 128;
    const int t  = threadIdx.x;
    const int wave = t >> 6;
    const int lane = t & 63;
    const int wr = wave >> 1;   // c half
    const int wc = wave & 1;    // i half
    const int l15 = lane & 15;
    const int quad = lane >> 4;

    __shared__ __align__(16) short lA[128 * 32];  // [c][j] bf16
    __shared__ __align__(16) short lB[128 * 32];  // [i][j] bf16

    const unsigned short* pV = vbf + (size_t)b * C * L;
    const unsigned short* pP = attnbf + (size_t)b * L * L;

    f32x4 acc[4][4] = {};

    for (int j0 = 0; j0 < L; j0 += 32) {
        // stage 128x32 bf16 tiles (8 KB each) via width-16 global_load_lds
        #pragma unroll
        for (int it = 0; it < 2; ++it) {
            int chunk = it * 256 + t;
            int row = chunk >> 2, cb = chunk & 3;
            int lbase = (it * 256 + wave * 64) * 16;  // wave-uniform LDS byte base
            gload_lds16(pV + (size_t)(c0 + row) * L + j0 + cb * 8, (char*)lA + lbase);
            gload_lds16(pP + (size_t)(i0 + row) * L + j0 + cb * 8, (char*)lB + lbase);
        }
        __syncthreads();

        frag_ab af[4], bfr[4];
        #pragma unroll
        for (int m = 0; m < 4; ++m)
            af[m] = *(const frag_ab*)&lA[(wr * 64 + m * 16 + l15) * 32 + quad * 8];
        #pragma unroll
        for (int n = 0; n < 4; ++n)
            bfr[n] = *(const frag_ab*)&lB[(wc * 64 + n * 16 + l15) * 32 + quad * 8];
        #pragma unroll
        for (int m = 0; m < 4; ++m)
            #pragma unroll
            for (int n = 0; n < 4; ++n)
                acc[m][n] = __builtin_amdgcn_mfma_f32_16x16x32_bf16(
                    af[m], bfr[n], acc[m][n], 0, 0, 0);
        __syncthreads();
    }

    const float g = gamma[0];
    #pragma unroll
    for (int m = 0; m < 4; ++m) {
        #pragma unroll
        for (int n = 0; n < 4; ++n) {
            #pragma unroll
            for (int r = 0; r < 4; ++r) {
                int c = c0 + wr * 64 + m * 16 + quad * 4 + r;
                int i = i0 + wc * 64 + n * 16 + l15;
                size_t off = ((size_t)b * C + c) * L + i;
                out[off] = fmaf(g, acc[m][n][r], x[off]);
            }
        }
    }
}

// ---------------------------------------------------------------------------
extern "C" void kernel_launch(void* const* d_in, const int* in_sizes, int n_in,
                              void* d_out, int out_size, void* d_ws, size_t ws_size,
                              hipStream_t stream)
{
    const float* x     = (const float*)d_in[0];
    const float* qw    = (const float*)d_in[1];
    const float* qb    = (const float*)d_in[2];
    const float* kw    = (const float*)d_in[3];
    const float* kb    = (const float*)d_in[4];
    const float* vw    = (const float*)d_in[5];
    const float* vb    = (const float*)d_in[6];
    const float* gamma = (const float*)d_in[7];

    float* out  = (float*)d_out;                       // (B, C, L)
    float* attn = (float*)d_out + (size_t)B * C * L;   // (B, L, L)

    // ws layout: y fp32 (B,256,L) | vbf bf16 (B,C,L) | attnbf bf16 (B,L,L)
    float* y = (float*)d_ws;                                              // 16 MB
    unsigned short* vbf    = (unsigned short*)((char*)d_ws + (size_t)16777216);  // 16 MB
    unsigned short* attnbf = (unsigned short*)((char*)d_ws + (size_t)33554432);  // 64 MB

    proj_kernel<<<dim3(L / 64, 768 / 64, B), 256, 0, stream>>>(
        x, qw, qb, kw, kb, vw, vb, y, vbf);
    energy_kernel<<<dim3(L / 64, L / 64, B), 256, 0, stream>>>(y, attn);
    softmax_kernel<<<B * L, 256, 0, stream>>>(attn, attnbf);
    out_mfma_kernel<<<dim3(L / 128, C / 128, B), 256, 0, stream>>>(
        vbf, attnbf, x, gamma, out);
}

// Round 3
// 393.155 us; speedup vs baseline: 3.7987x; 1.5997x over previous
//
#include <hip/hip_runtime.h>
#include <math.h>

#define B 8
#define C 512
#define L 2048
#define CQ 128

// gfx950 mfma_f32_16x16x32_bf16: 8 bf16 in (4 VGPR) / 4 f32 acc
using frag_ab = __attribute__((ext_vector_type(8))) short;
using f32x4   = __attribute__((ext_vector_type(4))) float;

__device__ __forceinline__ unsigned short f2bf(float f) {
    union { float f; unsigned int u; } v; v.f = f;
    unsigned int u = v.u + 0x7FFFu + ((v.u >> 16) & 1u);  // RNE
    return (unsigned short)(u >> 16);
}
__device__ __forceinline__ float bf2f(unsigned short h) {
    union { unsigned int u; float f; } v; v.u = ((unsigned int)h) << 16;
    return v.f;
}
__device__ __forceinline__ void gload_lds16(const void* g, void* l) {
    __builtin_amdgcn_global_load_lds(
        (__attribute__((address_space(1))) void*)g,
        (__attribute__((address_space(3))) void*)l, 16, 0, 0);
}

// ---------------------------------------------------------------------------
// P0: x (B,C,L) fp32 -> xt_hi/xt_lo (B,L,C) bf16 split, via LDS transpose
// ---------------------------------------------------------------------------
__global__ __launch_bounds__(256) void xpose_kernel(
    const float* __restrict__ x,
    unsigned short* __restrict__ xh, unsigned short* __restrict__ xl)
{
    const int b = blockIdx.z, c0 = blockIdx.y * 64, l0 = blockIdx.x * 64;
    const int t = threadIdx.x;
    __shared__ float Ts[64][65];
    const float* xb = x + (size_t)b * C * L;

    const int ll4 = (t & 15) * 4, cc = t >> 4;
    #pragma unroll
    for (int p = 0; p < 4; ++p) {
        float4 v = *(const float4*)(xb + (size_t)(c0 + cc + p * 16) * L + l0 + ll4);
        Ts[cc + p * 16][ll4 + 0] = v.x;
        Ts[cc + p * 16][ll4 + 1] = v.y;
        Ts[cc + p * 16][ll4 + 2] = v.z;
        Ts[cc + p * 16][ll4 + 3] = v.w;
    }
    __syncthreads();
    const int c4 = (t & 15) * 4, lr = t >> 4;
    #pragma unroll
    for (int p = 0; p < 4; ++p) {
        int l = lr + p * 16;
        float vr[4];
        #pragma unroll
        for (int r = 0; r < 4; ++r) vr[r] = Ts[c4 + r][l];
        ushort4 h, lo;
        h.x = f2bf(vr[0]); lo.x = f2bf(vr[0] - bf2f(h.x));
        h.y = f2bf(vr[1]); lo.y = f2bf(vr[1] - bf2f(h.y));
        h.z = f2bf(vr[2]); lo.z = f2bf(vr[2] - bf2f(h.z));
        h.w = f2bf(vr[3]); lo.w = f2bf(vr[3] - bf2f(h.w));
        size_t off = ((size_t)b * L + l0 + l) * C + c0 + c4;
        *(ushort4*)(xh + off) = h;
        *(ushort4*)(xl + off) = lo;
    }
}

// ---------------------------------------------------------------------------
// K1a: q/k projection, transposed output, split-bf16 MFMA (3 passes).
//      D[l][d] = sum_c xt[l][c] * w[d][c] + bias[d]  -> qt/kt hi+lo (B,L,128)
//      blockIdx.y: 0 = q, 1 = k.  128x128 tile, BK=32.
// ---------------------------------------------------------------------------
__global__ __launch_bounds__(256) void proj_qk_kernel(
    const unsigned short* __restrict__ xh, const unsigned short* __restrict__ xl,
    const float* __restrict__ qw, const float* __restrict__ qb,
    const float* __restrict__ kw, const float* __restrict__ kb,
    unsigned short* __restrict__ qth, unsigned short* __restrict__ qtl,
    unsigned short* __restrict__ kth, unsigned short* __restrict__ ktl)
{
    const int b  = blockIdx.z;
    const int l0 = blockIdx.x * 128;
    const bool isK = (blockIdx.y != 0);
    const float* w    = isK ? kw : qw;
    const float* bias = isK ? kb : qb;
    unsigned short* oh = isK ? kth : qth;
    unsigned short* ol = isK ? ktl : qtl;

    const int t = threadIdx.x, wave = t >> 6, lane = t & 63;
    const int wr = wave >> 1, wc = wave & 1, l15 = lane & 15, quad = lane >> 4;

    __shared__ __align__(16) short lAh[128 * 32], lAl[128 * 32];
    __shared__ __align__(16) short lBh[128 * 32], lBl[128 * 32];

    const unsigned short* pxh = xh + (size_t)b * L * C;
    const unsigned short* pxl = xl + (size_t)b * L * C;

    f32x4 acc[4][4] = {};

    for (int c0 = 0; c0 < C; c0 += 32) {
        #pragma unroll
        for (int it = 0; it < 2; ++it) {
            int chunk = it * 256 + t;
            int row = chunk >> 2, cb = chunk & 3;
            int lbase = (it * 256 + wave * 64) * 16;
            gload_lds16(pxh + (size_t)(l0 + row) * C + c0 + cb * 8, (char*)lAh + lbase);
            gload_lds16(pxl + (size_t)(l0 + row) * C + c0 + cb * 8, (char*)lAl + lbase);
        }
        {
            int cc4 = (t & 7) * 4, oo = t >> 3;
            #pragma unroll
            for (int p = 0; p < 4; ++p) {
                int o = oo + p * 32;
                float4 w4 = *(const float4*)(w + (size_t)o * C + c0 + cc4);
                ushort4 h, lo;
                h.x = f2bf(w4.x); lo.x = f2bf(w4.x - bf2f(h.x));
                h.y = f2bf(w4.y); lo.y = f2bf(w4.y - bf2f(h.y));
                h.z = f2bf(w4.z); lo.z = f2bf(w4.z - bf2f(h.z));
                h.w = f2bf(w4.w); lo.w = f2bf(w4.w - bf2f(h.w));
                *(ushort4*)(&lBh[o * 32 + cc4]) = h;
                *(ushort4*)(&lBl[o * 32 + cc4]) = lo;
            }
        }
        __syncthreads();

        frag_ab ah[4], al_[4], bh[4], bl_[4];
        #pragma unroll
        for (int m = 0; m < 4; ++m) {
            ah[m]  = *(const frag_ab*)&lAh[(wr * 64 + m * 16 + l15) * 32 + quad * 8];
            al_[m] = *(const frag_ab*)&lAl[(wr * 64 + m * 16 + l15) * 32 + quad * 8];
        }
        #pragma unroll
        for (int n = 0; n < 4; ++n) {
            bh[n]  = *(const frag_ab*)&lBh[(wc * 64 + n * 16 + l15) * 32 + quad * 8];
            bl_[n] = *(const frag_ab*)&lBl[(wc * 64 + n * 16 + l15) * 32 + quad * 8];
        }
        #pragma unroll
        for (int m = 0; m < 4; ++m)
            #pragma unroll
            for (int n = 0; n < 4; ++n) {
                acc[m][n] = __builtin_amdgcn_mfma_f32_16x16x32_bf16(ah[m],  bh[n],  acc[m][n], 0, 0, 0);
                acc[m][n] = __builtin_amdgcn_mfma_f32_16x16x32_bf16(ah[m],  bl_[n], acc[m][n], 0, 0, 0);
                acc[m][n] = __builtin_amdgcn_mfma_f32_16x16x32_bf16(al_[m], bh[n],  acc[m][n], 0, 0, 0);
            }
        __syncthreads();
    }

    #pragma unroll
    for (int m = 0; m < 4; ++m)
        #pragma unroll
        for (int n = 0; n < 4; ++n) {
            int d = wc * 64 + n * 16 + l15;
            float bs = bias[d];
            #pragma unroll
            for (int r = 0; r < 4; ++r) {
                int l = l0 + wr * 64 + m * 16 + quad * 4 + r;
                float v = acc[m][n][r] + bs;
                unsigned short h = f2bf(v);
                unsigned short lo = f2bf(v - bf2f(h));
                size_t off = ((size_t)b * L + l) * CQ + d;
                oh[off] = h;
                ol[off] = lo;
            }
        }
}

// ---------------------------------------------------------------------------
// K1b: v projection, plain bf16 MFMA. D[c][l] = sum_k vw[c][k] xt[l][k] + vb[c]
// ---------------------------------------------------------------------------
__global__ __launch_bounds__(256) void proj_v_kernel(
    const unsigned short* __restrict__ xh,
    const float* __restrict__ vw, const float* __restrict__ vb,
    unsigned short* __restrict__ vbf)
{
    const int b  = blockIdx.z;
    const int c0 = blockIdx.y * 128;
    const int l0 = blockIdx.x * 128;

    const int t = threadIdx.x, wave = t >> 6, lane = t & 63;
    const int wr = wave >> 1, wc = wave & 1, l15 = lane & 15, quad = lane >> 4;

    __shared__ __align__(16) short lA[128 * 32];   // vw tile [c_out][k]
    __shared__ __align__(16) short lB[128 * 32];   // xt tile [l][k]

    const unsigned short* pxh = xh + (size_t)b * L * C;

    f32x4 acc[4][4] = {};

    for (int k0 = 0; k0 < C; k0 += 32) {
        {
            int kk4 = (t & 7) * 4, oo = t >> 3;
            #pragma unroll
            for (int p = 0; p < 4; ++p) {
                int o = oo + p * 32;
                float4 w4 = *(const float4*)(vw + (size_t)(c0 + o) * C + k0 + kk4);
                ushort4 h;
                h.x = f2bf(w4.x); h.y = f2bf(w4.y); h.z = f2bf(w4.z); h.w = f2bf(w4.w);
                *(ushort4*)(&lA[o * 32 + kk4]) = h;
            }
        }
        #pragma unroll
        for (int it = 0; it < 2; ++it) {
            int chunk = it * 256 + t;
            int row = chunk >> 2, cb = chunk & 3;
            int lbase = (it * 256 + wave * 64) * 16;
            gload_lds16(pxh + (size_t)(l0 + row) * C + k0 + cb * 8, (char*)lB + lbase);
        }
        __syncthreads();

        frag_ab af[4], bfr[4];
        #pragma unroll
        for (int m = 0; m < 4; ++m)
            af[m] = *(const frag_ab*)&lA[(wr * 64 + m * 16 + l15) * 32 + quad * 8];
        #pragma unroll
        for (int n = 0; n < 4; ++n)
            bfr[n] = *(const frag_ab*)&lB[(wc * 64 + n * 16 + l15) * 32 + quad * 8];
        #pragma unroll
        for (int m = 0; m < 4; ++m)
            #pragma unroll
            for (int n = 0; n < 4; ++n)
                acc[m][n] = __builtin_amdgcn_mfma_f32_16x16x32_bf16(af[m], bfr[n], acc[m][n], 0, 0, 0);
        __syncthreads();
    }

    #pragma unroll
    for (int m = 0; m < 4; ++m)
        #pragma unroll
        for (int n = 0; n < 4; ++n)
            #pragma unroll
            for (int r = 0; r < 4; ++r) {
                int c = c0 + wr * 64 + m * 16 + quad * 4 + r;
                int l = l0 + wc * 64 + n * 16 + l15;
                vbf[((size_t)b * C + c) * L + l] = f2bf(acc[m][n][r] + vb[c]);
            }
}

// ---------------------------------------------------------------------------
// K2: energy[i][j] = sum_d qt[i][d] kt[j][d], split-bf16 (3 passes), K=128
// ---------------------------------------------------------------------------
__global__ __launch_bounds__(256) void energy_mfma_kernel(
    const unsigned short* __restrict__ qth, const unsigned short* __restrict__ qtl,
    const unsigned short* __restrict__ kth, const unsigned short* __restrict__ ktl,
    float* __restrict__ attn)
{
    const int b  = blockIdx.z;
    const int i0 = blockIdx.y * 128;
    const int j0 = blockIdx.x * 128;

    const int t = threadIdx.x, wave = t >> 6, lane = t & 63;
    const int wr = wave >> 1, wc = wave & 1, l15 = lane & 15, quad = lane >> 4;

    __shared__ __align__(16) short lQh[128 * 32], lQl[128 * 32];
    __shared__ __align__(16) short lKh[128 * 32], lKl[128 * 32];

    const unsigned short* pqh = qth + (size_t)b * L * CQ;
    const unsigned short* pql = qtl + (size_t)b * L * CQ;
    const unsigned short* pkh = kth + (size_t)b * L * CQ;
    const unsigned short* pkl = ktl + (size_t)b * L * CQ;

    f32x4 acc[4][4] = {};

    for (int d0 = 0; d0 < CQ; d0 += 32) {
        #pragma unroll
        for (int it = 0; it < 2; ++it) {
            int chunk = it * 256 + t;
            int row = chunk >> 2, cb = chunk & 3;
            int lbase = (it * 256 + wave * 64) * 16;
            gload_lds16(pqh + (size_t)(i0 + row) * CQ + d0 + cb * 8, (char*)lQh + lbase);
            gload_lds16(pql + (size_t)(i0 + row) * CQ + d0 + cb * 8, (char*)lQl + lbase);
            gload_lds16(pkh + (size_t)(j0 + row) * CQ + d0 + cb * 8, (char*)lKh + lbase);
            gload_lds16(pkl + (size_t)(j0 + row) * CQ + d0 + cb * 8, (char*)lKl + lbase);
        }
        __syncthreads();

        frag_ab ah[4], al_[4], bh[4], bl_[4];
        #pragma unroll
        for (int m = 0; m < 4; ++m) {
            ah[m]  = *(const frag_ab*)&lQh[(wr * 64 + m * 16 + l15) * 32 + quad * 8];
            al_[m] = *(const frag_ab*)&lQl[(wr * 64 + m * 16 + l15) * 32 + quad * 8];
        }
        #pragma unroll
        for (int n = 0; n < 4; ++n) {
            bh[n]  = *(const frag_ab*)&lKh[(wc * 64 + n * 16 + l15) * 32 + quad * 8];
            bl_[n] = *(const frag_ab*)&lKl[(wc * 64 + n * 16 + l15) * 32 + quad * 8];
        }
        #pragma unroll
        for (int m = 0; m < 4; ++m)
            #pragma unroll
            for (int n = 0; n < 4; ++n) {
                acc[m][n] = __builtin_amdgcn_mfma_f32_16x16x32_bf16(ah[m],  bh[n],  acc[m][n], 0, 0, 0);
                acc[m][n] = __builtin_amdgcn_mfma_f32_16x16x32_bf16(ah[m],  bl_[n], acc[m][n], 0, 0, 0);
                acc[m][n] = __builtin_amdgcn_mfma_f32_16x16x32_bf16(al_[m], bh[n],  acc[m][n], 0, 0, 0);
            }
        __syncthreads();
    }

    #pragma unroll
    for (int m = 0; m < 4; ++m)
        #pragma unroll
        for (int n = 0; n < 4; ++n)
            #pragma unroll
            for (int r = 0; r < 4; ++r) {
                int i = i0 + wr * 64 + m * 16 + quad * 4 + r;
                int j = j0 + wc * 64 + n * 16 + l15;
                attn[((size_t)b * L + i) * L + j] = acc[m][n][r];
            }
}

// ---------------------------------------------------------------------------
// K3: row softmax; fp32 in-place + bf16 copy to attnbf
// ---------------------------------------------------------------------------
__global__ __launch_bounds__(256) void softmax_kernel(
    float* __restrict__ attn, unsigned short* __restrict__ attnbf)
{
    const size_t row = blockIdx.x;
    float* p = attn + row * (size_t)L;
    unsigned short* pb = attnbf + row * (size_t)L;
    const int tid = threadIdx.x;
    const int wave = tid >> 6, lane = tid & 63;

    float v[8];
    #pragma unroll
    for (int kk = 0; kk < 8; ++kk) v[kk] = p[tid + kk * 256];

    float m = v[0];
    #pragma unroll
    for (int kk = 1; kk < 8; ++kk) m = fmaxf(m, v[kk]);
    #pragma unroll
    for (int off = 32; off >= 1; off >>= 1) m = fmaxf(m, __shfl_xor(m, off));

    __shared__ float red[4];
    if (lane == 0) red[wave] = m;
    __syncthreads();
    m = fmaxf(fmaxf(red[0], red[1]), fmaxf(red[2], red[3]));
    __syncthreads();

    float s = 0.f;
    #pragma unroll
    for (int kk = 0; kk < 8; ++kk) { v[kk] = __expf(v[kk] - m); s += v[kk]; }
    #pragma unroll
    for (int off = 32; off >= 1; off >>= 1) s += __shfl_xor(s, off);
    if (lane == 0) red[wave] = s;
    __syncthreads();
    s = (red[0] + red[1]) + (red[2] + red[3]);

    const float inv = 1.0f / s;
    #pragma unroll
    for (int kk = 0; kk < 8; ++kk) {
        float r = v[kk] * inv;
        p[tid + kk * 256] = r;
        pb[tid + kk * 256] = f2bf(r);
    }
}

// ---------------------------------------------------------------------------
// K4: out[c][i] = gamma * sum_j v[c][j]*attn[i][j] + x[c][i]  (bf16 MFMA)
// ---------------------------------------------------------------------------
__global__ __launch_bounds__(256) void out_mfma_kernel(
    const unsigned short* __restrict__ vbf,
    const unsigned short* __restrict__ attnbf,
    const float* __restrict__ x, const float* __restrict__ gamma,
    float* __restrict__ out)
{
    const int b  = blockIdx.z;
    const int c0 = blockIdx.y * 128;
    const int i0 = blockIdx.x * 128;
    const int t  = threadIdx.x;
    const int wave = t >> 6, lane = t & 63;
    const int wr = wave >> 1, wc = wave & 1;
    const int l15 = lane & 15, quad = lane >> 4;

    __shared__ __align__(16) short lA[128 * 32];
    __shared__ __align__(16) short lB[128 * 32];

    const unsigned short* pV = vbf + (size_t)b * C * L;
    const unsigned short* pP = attnbf + (size_t)b * L * L;

    f32x4 acc[4][4] = {};

    for (int j0 = 0; j0 < L; j0 += 32) {
        #pragma unroll
        for (int it = 0; it < 2; ++it) {
            int chunk = it * 256 + t;
            int row = chunk >> 2, cb = chunk & 3;
            int lbase = (it * 256 + wave * 64) * 16;
            gload_lds16(pV + (size_t)(c0 + row) * L + j0 + cb * 8, (char*)lA + lbase);
            gload_lds16(pP + (size_t)(i0 + row) * L + j0 + cb * 8, (char*)lB + lbase);
        }
        __syncthreads();

        frag_ab af[4], bfr[4];
        #pragma unroll
        for (int m = 0; m < 4; ++m)
            af[m] = *(const frag_ab*)&lA[(wr * 64 + m * 16 + l15) * 32 + quad * 8];
        #pragma unroll
        for (int n = 0; n < 4; ++n)
            bfr[n] = *(const frag_ab*)&lB[(wc * 64 + n * 16 + l15) * 32 + quad * 8];
        #pragma unroll
        for (int m = 0; m < 4; ++m)
            #pragma unroll
            for (int n = 0; n < 4; ++n)
                acc[m][n] = __builtin_amdgcn_mfma_f32_16x16x32_bf16(
                    af[m], bfr[n], acc[m][n], 0, 0, 0);
        __syncthreads();
    }

    const float g = gamma[0];
    #pragma unroll
    for (int m = 0; m < 4; ++m)
        #pragma unroll
        for (int n = 0; n < 4; ++n)
            #pragma unroll
            for (int r = 0; r < 4; ++r) {
                int c = c0 + wr * 64 + m * 16 + quad * 4 + r;
                int i = i0 + wc * 64 + n * 16 + l15;
                size_t off = ((size_t)b * C + c) * L + i;
                out[off] = fmaf(g, acc[m][n][r], x[off]);
            }
}

// ---------------------------------------------------------------------------
extern "C" void kernel_launch(void* const* d_in, const int* in_sizes, int n_in,
                              void* d_out, int out_size, void* d_ws, size_t ws_size,
                              hipStream_t stream)
{
    const float* x     = (const float*)d_in[0];
    const float* qw    = (const float*)d_in[1];
    const float* qb    = (const float*)d_in[2];
    const float* kw    = (const float*)d_in[3];
    const float* kb    = (const float*)d_in[4];
    const float* vw    = (const float*)d_in[5];
    const float* vb    = (const float*)d_in[6];
    const float* gamma = (const float*)d_in[7];

    float* out  = (float*)d_out;                       // (B, C, L)
    float* attn = (float*)d_out + (size_t)B * C * L;   // (B, L, L)

    const size_t MiB = 1048576;
    // ws layout (96 MiB total):
    //   [0,32)   MiB: xt_hi(16) + xt_lo(16)  -- consumed by proj kernels
    //   [0,64)   MiB: attnbf (reuses xt region; written by softmax AFTER proj)
    //   [64,80)  MiB: qt_hi(4) qt_lo(4) kt_hi(4) kt_lo(4)
    //   [80,96)  MiB: vbf(16)
    unsigned short* xt_hi  = (unsigned short*)d_ws;
    unsigned short* xt_lo  = (unsigned short*)((char*)d_ws + 16 * MiB);
    unsigned short* attnbf = (unsigned short*)d_ws;
    unsigned short* qth    = (unsigned short*)((char*)d_ws + 64 * MiB);
    unsigned short* qtl    = (unsigned short*)((char*)d_ws + 68 * MiB);
    unsigned short* kth    = (unsigned short*)((char*)d_ws + 72 * MiB);
    unsigned short* ktl    = (unsigned short*)((char*)d_ws + 76 * MiB);
    unsigned short* vbf    = (unsigned short*)((char*)d_ws + 80 * MiB);

    xpose_kernel<<<dim3(L / 64, C / 64, B), 256, 0, stream>>>(x, xt_hi, xt_lo);
    proj_qk_kernel<<<dim3(L / 128, 2, B), 256, 0, stream>>>(
        xt_hi, xt_lo, qw, qb, kw, kb, qth, qtl, kth, ktl);
    proj_v_kernel<<<dim3(L / 128, C / 128, B), 256, 0, stream>>>(
        xt_hi, vw, vb, vbf);
    energy_mfma_kernel<<<dim3(L / 128, L / 128, B), 256, 0, stream>>>(
        qth, qtl, kth, ktl, attn);
    softmax_kernel<<<B * L, 256, 0, stream>>>(attn, attnbf);
    out_mfma_kernel<<<dim3(L / 128, C / 128, B), 256, 0, stream>>>(
        vbf, attnbf, x, gamma, out);
}